// Round 15
// baseline (44.497 us; speedup 1.0000x reference)
//
#include <hip/hip_runtime.h>

// DifferentiableCIndexLoss:
//   mask[i,j] = (t[i] < t[j]) && (e[i]==1)
//   loss = sum sigmoid((r[j]-r[i])/SIGMA) * mask ;  count = sum mask
//   out  = loss / (count + 1e-6)
//
// R15 = R14 (best-equal, 40.6us) + DIAGNOSTIC PROBE NODE (k_probe).
// Five targeted k_main changes in a row were null: the ~27us main vs ~13us
// issue floor gap survived rcp-pairing, block-geometry, staging-path, and
// ILP changes. rocprof top-5 is flooded by 39us harness poison-fills, so
// kernels <39us are invisible. k_probe = k_main's exact skeleton (row loads,
// LDS tile+barriers, 64-iter LDS-broadcast loop, reduce, store) with math
// gutted to 4 independent FMAs (no rcp/cmp/count), writing to scratch pL2.
// Its duration = total_R15 - total_R14, splitting main into
// {skeleton+ramp+stall} vs {math issue}. Decision rule in journal.
// k_main, compact, finalize are byte-identical to R14 (clean delta).

#define BLOCK 256
#define RPT 8                        // rows per thread
#define ROWS_PER_TILE (BLOCK * RPT)  // 2048
#define JTILE 64                     // cols per tile
#define NCOLGRP 256                  // 16384/64
#define GRID_MAIN 1024               // = nrc(4) * 256

__device__ __forceinline__ float fast_exp2(float x) { return __builtin_amdgcn_exp2f(x); }
__device__ __forceinline__ float fast_rcp(float x)  { return __builtin_amdgcn_rcpf(x); }
__device__ __forceinline__ float clamp60(float x)   { return fminf(fmaxf(x, -60.0f), 60.0f); }

// ---- 1) transform cols + compact active rows (block-aggregated cursor) ------
__global__ __launch_bounds__(BLOCK) void k_compact(
    const float* __restrict__ r, const float* __restrict__ t,
    const int* __restrict__ ev, int B, float kscale,
    int* __restrict__ cursor,          // zeroed by memset; final value = nactive
    float2* __restrict__ sI, float2* __restrict__ sJ) {
    const int tid = threadIdx.x;
    int g = blockIdx.x * BLOCK + tid;
    if (g >= B) return;
    float tv = t[g];
    float s  = clamp60(r[g] * kscale);
    sJ[g] = make_float2(fast_exp2(-s), tv);        // F_j = 2^{-s_j}
    bool pred = (ev[g] == 1);
    unsigned long long bal = __ballot(pred);
    int lane = tid & 63, wid = tid >> 6;
    int before = __popcll(bal & ((1ull << lane) - 1ull));
    int wcnt = __popcll(bal);
    __shared__ int wbase[BLOCK / 64];
    if (lane == 0) wbase[wid] = wcnt;
    __syncthreads();
    if (tid == 0) {
        int c0 = wbase[0], c1 = wbase[1], c2 = wbase[2], c3 = wbase[3];
        int b0 = atomicAdd(cursor, (c0 + c1) + (c2 + c3));  // ONE atomic/block
        wbase[0] = b0; wbase[1] = b0 + c0; wbase[2] = b0 + c0 + c1;
        wbase[3] = b0 + c0 + c1 + c2;
    }
    __syncthreads();
    if (pred) sI[wbase[wid] + before] = make_float2(fast_exp2(s), tv);
}

// ---- 2) main: all-pairs, RPT=8, independent accumulator chains (R14) --------
__global__ __launch_bounds__(BLOCK) void k_main(
    const float2* __restrict__ sI, const float2* __restrict__ sJ,
    const int* __restrict__ nactive_g,
    float* __restrict__ pL, unsigned int* __restrict__ pC) {

    const int tid = threadIdx.x;
    const int nactive = *nactive_g;
    const int nrc = (nactive + ROWS_PER_TILE - 1) / ROWS_PER_TILE;  // ~4
    const int ntiles = nrc * NCOLGRP;                                // ~1024

    __shared__ float2 tile[JTILE];

    float lsum = 0.0f;
    int   csum = 0;

    for (int tix = blockIdx.x; tix < ntiles; tix += gridDim.x) {
        int rc = tix >> 8;            // row chunk (ntiles = nrc*256)
        int cg = tix & (NCOLGRP - 1); // col group

        float E[RPT], T[RPT];
        int rbase = rc * ROWS_PER_TILE;
#pragma unroll
        for (int k = 0; k < RPT; ++k) {
            int rr = rbase + tid + (k << 8);
            if (rr < nactive) { float2 f = sI[rr]; E[k] = f.x; T[k] = f.y; }
            else              { E[k] = 1.0f; T[k] = 3.0f; }
        }

        __syncthreads();
        if (tid < JTILE) tile[tid] = sJ[(cg << 6) + tid];
        __syncthreads();

        float l[4] = {0.f, 0.f, 0.f, 0.f};
        int   c[4] = {0, 0, 0, 0};
#pragma unroll 4
        for (int jj = 0; jj < JTILE; ++jj) {
            float2 q = tile[jj];      // wave-uniform LDS broadcast
            float F = q.x, tj = q.y;
#pragma unroll
            for (int g2 = 0; g2 < 4; ++g2) {      // 4 independent pair-groups
                float u = __builtin_fmaf(E[2*g2],   F, 1.0f);
                float v = __builtin_fmaf(E[2*g2+1], F, 1.0f);
                float p = fminf(u * v, 3.0e38f);
                float rp = fast_rcp(p);
                bool m0 = T[2*g2]   < tj;
                bool m1 = T[2*g2+1] < tj;
                float num = (m0 ? v : 0.0f) + (m1 ? u : 0.0f);
                l[g2] = __builtin_fmaf(num, rp, l[g2]);
                c[g2] += m0 + m1;
            }
        }
        lsum += (l[0] + l[1]) + (l[2] + l[3]);
        csum += (c[0] + c[1]) + (c[2] + c[3]);
    }

#pragma unroll
    for (int off = 32; off > 0; off >>= 1) {
        lsum += __shfl_down(lsum, off);
        csum += __shfl_down(csum, off);
    }
    __shared__ float lw[BLOCK / 64];
    __shared__ int   cw[BLOCK / 64];
    int wid = tid >> 6;
    if ((tid & 63) == 0) { lw[wid] = lsum; cw[wid] = csum; }
    __syncthreads();
    if (tid == 0) {
        pL[blockIdx.x] = (lw[0] + lw[1]) + (lw[2] + lw[3]);
        pC[blockIdx.x] = (unsigned)((cw[0] + cw[1]) + (cw[2] + cw[3]));
    }
}

// ---- 2b) PROBE: k_main skeleton, math gutted to 4 indep FMAs ----------------
__global__ __launch_bounds__(BLOCK) void k_probe(
    const float2* __restrict__ sI, const float2* __restrict__ sJ,
    const int* __restrict__ nactive_g,
    float* __restrict__ pL2) {

    const int tid = threadIdx.x;
    const int nactive = *nactive_g;
    const int nrc = (nactive + ROWS_PER_TILE - 1) / ROWS_PER_TILE;
    const int ntiles = nrc * NCOLGRP;

    __shared__ float2 tile[JTILE];

    float lsum = 0.0f;

    for (int tix = blockIdx.x; tix < ntiles; tix += gridDim.x) {
        int rc = tix >> 8;
        int cg = tix & (NCOLGRP - 1);

        float E[RPT], T[RPT];
        int rbase = rc * ROWS_PER_TILE;
#pragma unroll
        for (int k = 0; k < RPT; ++k) {
            int rr = rbase + tid + (k << 8);
            if (rr < nactive) { float2 f = sI[rr]; E[k] = f.x; T[k] = f.y; }
            else              { E[k] = 1.0f; T[k] = 3.0f; }
        }

        __syncthreads();
        if (tid < JTILE) tile[tid] = sJ[(cg << 6) + tid];
        __syncthreads();

        // keep all 8 row values live without math: fold into accumulators
        float l[4];
#pragma unroll
        for (int g2 = 0; g2 < 4; ++g2)
            l[g2] = (E[2*g2+1] + T[2*g2]) * 1.0e-30f;

#pragma unroll 4
        for (int jj = 0; jj < JTILE; ++jj) {
            float2 q = tile[jj];      // same LDS broadcast as k_main
            float F = q.x, tj = q.y;
            l[0] = __builtin_fmaf(F,  E[0], l[0]);   // 4 independent FMAs,
            l[1] = __builtin_fmaf(F,  E[2], l[1]);   // no rcp / cmp / count
            l[2] = __builtin_fmaf(F,  E[4], l[2]);
            l[3] = __builtin_fmaf(tj, E[6], l[3]);
        }
        lsum += (l[0] + l[1]) + (l[2] + l[3]);
    }

#pragma unroll
    for (int off = 32; off > 0; off >>= 1)
        lsum += __shfl_down(lsum, off);
    __shared__ float lw[BLOCK / 64];
    int wid = tid >> 6;
    if ((tid & 63) == 0) lw[wid] = lsum;
    __syncthreads();
    if (tid == 0)
        pL2[blockIdx.x] = (lw[0] + lw[1]) + (lw[2] + lw[3]);   // scratch only
}

// ---- 3) finalize (reads pL/pC only; probe output unused) --------------------
__global__ __launch_bounds__(BLOCK) void k_finalize(
    const float* __restrict__ pL, const unsigned int* __restrict__ pC,
    int n, float* __restrict__ out) {
    double l = 0.0, c = 0.0;
    for (int i = threadIdx.x; i < n; i += BLOCK) {
        l += (double)pL[i];
        c += (double)pC[i];
    }
#pragma unroll
    for (int off = 32; off > 0; off >>= 1) {
        l += __shfl_down(l, off);
        c += __shfl_down(c, off);
    }
    __shared__ double lw[BLOCK / 64], cw[BLOCK / 64];
    int wid = threadIdx.x >> 6;
    if ((threadIdx.x & 63) == 0) { lw[wid] = l; cw[wid] = c; }
    __syncthreads();
    if (threadIdx.x == 0) {
        double L = (lw[0] + lw[1]) + (lw[2] + lw[3]);
        double C = (cw[0] + cw[1]) + (cw[2] + cw[3]);
        out[0] = (float)(L / (C + 1e-6));
    }
}

extern "C" void kernel_launch(void* const* d_in, const int* in_sizes, int n_in,
                              void* d_out, int out_size, void* d_ws, size_t ws_size,
                              hipStream_t stream) {
    const float* r  = (const float*)d_in[0];
    const float* t  = (const float*)d_in[1];
    const int*   ev = (const int*)d_in[2];
    float* out = (float*)d_out;
    const int B = in_sizes[0];   // 16384

    const float SIGMA = 0.1f;
    const float LOG2E = 1.4426950408889634f;
    const float kscale = LOG2E / SIGMA;

    char* ws = (char*)d_ws;
    int* cursor = (int*)ws;                        // [0,64): atomic cursor = nactive
    float2* sI  = (float2*)(ws + 4096);            // 128 KB (compacted rows: E, t)
    float2* sJ  = sI + B;                          // 128 KB (all cols: F, t)
    float*  pL  = (float*)(sJ + B);
    unsigned int* pC = (unsigned int*)(pL + GRID_MAIN);
    float*  pL2 = (float*)(pC + GRID_MAIN);        // probe scratch

    const int nblk = (B + BLOCK - 1) / BLOCK;      // 64

    hipMemsetAsync(ws, 0, 64, stream);
    k_compact<<<nblk, BLOCK, 0, stream>>>(r, t, ev, B, kscale, cursor, sI, sJ);
    k_main<<<GRID_MAIN, BLOCK, 0, stream>>>(sI, sJ, cursor, pL, pC);
    k_probe<<<GRID_MAIN, BLOCK, 0, stream>>>(sI, sJ, cursor, pL2);
    k_finalize<<<1, BLOCK, 0, stream>>>(pL, pC, GRID_MAIN, out);
}